// Round 1
// baseline (912.961 us; speedup 1.0000x reference)
//
#include <hip/hip_runtime.h>

#define RN      128   // REAL = TAG_SIZE + 2
#define START_T 126
#define END_T   127

__global__ __launch_bounds__(256)
void crf_nll_kernel(const float* __restrict__ X,
                    const int*   __restrict__ y,
                    const float* __restrict__ trans,
                    float* __restrict__ out,
                    int L)
{
    const int b   = blockIdx.x;
    const int tid = threadIdx.x;
    const int i   = tid & 127;     // output row (new tag)
    const int h   = tid >> 7;      // j-half, wave-uniform (waves 0,1: h=0; waves 2,3: h=1)
    const int wid = tid >> 6;      // wave id 0..3

    __shared__ float p[RN];        // exp(alpha - s)
    __shared__ float red[RN];      // cross-half partial sums
    __shared__ float wmax[2];
    __shared__ float wsum[2];
    __shared__ float tmp4[4];
    __shared__ float goldS;

    const float* Xb = X + (size_t)b * L * RN;
    const int*   yb = y + (size_t)b * L;

    // ---------------- gold path score ----------------
    float g = 0.0f;
    for (int t = tid; t < L; t += 256) {
        int yt = yb[t];
        int yp = (t == 0) ? START_T : yb[t - 1];
        g += trans[yt * RN + yp] + Xb[(size_t)t * RN + yt];
    }
    #pragma unroll
    for (int off = 1; off < 64; off <<= 1)
        g += __shfl_xor(g, off, 64);
    if ((tid & 63) == 0) tmp4[wid] = g;

    // ---------------- init forward state ----------------
    // alpha_init[j] = NEG except alpha[START]=0; m = max = 0; p = exp(alpha - 0)
    if (h == 0) p[i] = (i == START_T) ? 1.0f : 0.0f;

    // E[k] = exp(trans[i][h*64+k]) held in VGPRs for the whole kernel.
    // Masked entries (NEG=-1e4) -> exp underflows to exactly 0, preserving semantics.
    float E[64];
    {
        const float* tr = trans + i * RN + h * 64;
        #pragma unroll
        for (int k = 0; k < 64; ++k) E[k] = __expf(tr[k]);
    }

    __syncthreads();
    if (tid == 0) {
        goldS = tmp4[0] + tmp4[1] + tmp4[2] + tmp4[3]
              + trans[END_T * RN + yb[L - 1]];
    }

    float m = 0.0f;      // max(alpha_{t-1})  (stale-by-one subtractor for p)
    float s = 0.0f;      // subtractor actually baked into current p[]
    float alpha = 0.0f;  // this thread's alpha[i] (h==0 lanes only)

    float emit = (h == 0) ? Xb[i] : 0.0f;   // prefetch t=0

    for (int t = 0; t < L; ++t) {
        int tn = (t + 1 < L) ? (t + 1) : t;
        float emit_next = (h == 0) ? Xb[(size_t)tn * RN + i] : 0.0f;

        // partial = sum_k E[k] * p[h*64+k]   (p reads are wave-uniform -> LDS broadcast)
        const float4* pp4 = (const float4*)(p + h * 64);
        float a0 = 0.f, a1 = 0.f, a2 = 0.f, a3 = 0.f;
        #pragma unroll
        for (int k4 = 0; k4 < 16; ++k4) {
            float4 pv = pp4[k4];
            a0 = fmaf(E[4 * k4 + 0], pv.x, a0);
            a1 = fmaf(E[4 * k4 + 1], pv.y, a1);
            a2 = fmaf(E[4 * k4 + 2], pv.z, a2);
            a3 = fmaf(E[4 * k4 + 3], pv.w, a3);
        }
        float partial = (a0 + a1) + (a2 + a3);
        if (h == 1) red[i] = partial;
        __syncthreads();                       // barrier A: red visible, prev-iter p reads done
        if (h == 0) {
            float v = partial + red[i];
            v = fmaxf(v, 1e-30f);              // clamp: keeps -inf out while staying ~exactly 0 in the sum
            alpha = __logf(v) + s + emit;
            float wm = alpha;
            #pragma unroll
            for (int off = 1; off < 64; off <<= 1)
                wm = fmaxf(wm, __shfl_xor(wm, off, 64));
            if ((tid & 63) == 0) wmax[wid] = wm;
            p[i] = __expf(alpha - m);          // new p with subtractor m (stale-by-one max: bounded)
        }
        __syncthreads();                       // barrier B: p & wmax visible
        s = m;                                 // subtractor baked into the p[] we just wrote
        m = fmaxf(wmax[0], wmax[1]);           // fresh max(alpha_t) for next iteration
        emit = emit_next;
    }
    __syncthreads();

    // ---------------- logZ = logsumexp(alpha + trans[END, :]) ----------------
    float z = -3.0e38f;
    if (h == 0) {
        z = alpha + trans[END_T * RN + i];
        float zm = z;
        #pragma unroll
        for (int off = 1; off < 64; off <<= 1)
            zm = fmaxf(zm, __shfl_xor(zm, off, 64));
        if ((tid & 63) == 0) wmax[wid] = zm;
    }
    __syncthreads();
    float zmax = fmaxf(wmax[0], wmax[1]);
    if (h == 0) {
        float e = __expf(z - zmax);
        #pragma unroll
        for (int off = 1; off < 64; off <<= 1)
            e += __shfl_xor(e, off, 64);
        if ((tid & 63) == 0) wsum[wid] = e;
    }
    __syncthreads();
    if (tid == 0) {
        float logZ = zmax + __logf(wsum[0] + wsum[1]);
        out[b] = logZ - goldS;
    }
}

extern "C" void kernel_launch(void* const* d_in, const int* in_sizes, int n_in,
                              void* d_out, int out_size, void* d_ws, size_t ws_size,
                              hipStream_t stream) {
    const float* X     = (const float*)d_in[0];
    const int*   y     = (const int*)d_in[1];
    const float* trans = (const float*)d_in[2];
    float*       out   = (float*)d_out;

    const int B = out_size;            // 256
    const int L = in_sizes[1] / B;     // 1024

    crf_nll_kernel<<<dim3(B), dim3(256), 0, stream>>>(X, y, trans, out, L);
}

// Round 2
// 609.967 us; speedup vs baseline: 1.4967x; 1.4967x over previous
//
#include <hip/hip_runtime.h>

#define RN      128   // REAL
#define START_T 126
#define END_T   127

// DPP cross-lane helper (all-lane-active contexts only)
#define FDPP(x, ctrl) __int_as_float(__builtin_amdgcn_update_dpp(0, __float_as_int(x), (ctrl), 0xF, 0xF, true))

// padded p layout: row r -> word (r>>4)*20 + (r&15); chunk c at word 20c (16B aligned)
__device__ __forceinline__ int pword(int r) { return ((r >> 4) * 20) + (r & 15); }

__global__ __launch_bounds__(512)
void crf_nll_kernel(const float* __restrict__ X,
                    const int*   __restrict__ y,
                    const float* __restrict__ trans,
                    float* __restrict__ out, int L)
{
    const int b   = blockIdx.x;
    const int tid = threadIdx.x;
    const int s   = tid & 7;    // j-chunk 0..7 (16 wide)
    const int rr  = tid >> 3;   // 0..63 -> rows rr and rr+64
    const int wv  = tid >> 6;   // wave 0..7

    __shared__ __align__(16) float pbuf[2][160];  // double-buffered scaled probs, padded
    __shared__ __align__(16) float wh[16];        // per-half-wave maxes
    __shared__ float tmp8[8];

    const float* Xb = X + (size_t)b * (size_t)L * RN;
    const int*   yb = y + (size_t)b * L;

    // ---------------- gold path score ----------------
    float g = 0.f;
    for (int t = tid; t < L; t += 512) {
        int yt = yb[t];
        int yp = t ? yb[t - 1] : START_T;
        g += trans[yt * RN + yp] + Xb[(size_t)t * RN + yt];
    }
    #pragma unroll
    for (int off = 1; off < 64; off <<= 1) g += __shfl_xor(g, off, 64);
    if ((tid & 63) == 0) tmp8[wv] = g;

    // zero p buffers
    for (int w = tid; w < 2 * 160; w += 512) ((float*)pbuf)[w] = 0.f;

    // E held in VGPRs: exp(trans) for rows rr and rr+64, chunk s.
    // Masked entries (-1e4) underflow to exactly 0 -> semiring mask preserved.
    float E0[16], E1[16];
    {
        const float* t0 = trans + rr * RN + s * 16;
        const float* t1 = trans + (rr + 64) * RN + s * 16;
        #pragma unroll
        for (int k = 0; k < 16; ++k) { E0[k] = __expf(t0[k]); E1[k] = __expf(t1[k]); }
    }

    const bool w0 = (s == 0), w1 = (s == 1);
    const bool writer = w0 || w1;
    const int  myrow = rr + (w1 ? 64 : 0);

    __syncthreads();
    float goldv = 0.f;
    if (tid == 0) {
        float gg = 0.f;
        #pragma unroll
        for (int i = 0; i < 8; ++i) gg += tmp8[i];
        goldv = gg + trans[END_T * RN + yb[L - 1]];
        pbuf[0][pword(START_T)] = 1.0f;   // init state: onehot(START)
    }

    // emit pipeline, depth 2: ee = exp(X[t]), xld = raw X[t+1]
    float ee = 1.f, xld = 0.f;
    if (writer) {
        ee  = __expf(Xb[myrow]);
        xld = (L > 1) ? Xb[RN + myrow] : 0.f;
    }
    __syncthreads();

    float logscale = 0.f, inv = 1.f;
    int cur = 0;
    for (int t = 0; t < L; ++t) {
        // prefetch X[t+2] (HBM latency hidden behind ~2 steps)
        float xnext = 0.f;
        if (writer) {
            int tt = (t + 2 < L) ? (t + 2) : (L - 1);
            xnext = Xb[(size_t)tt * RN + myrow];
        }

        // read my 16-wide chunk of p (conflict-free broadcast b128 reads)
        const float* P = pbuf[cur] + 20 * s;
        float pq[16];
        {
            const float4* P4 = (const float4*)P;
            float4 q0 = P4[0], q1 = P4[1], q2 = P4[2], q3 = P4[3];
            pq[0]=q0.x; pq[1]=q0.y; pq[2]=q0.z;  pq[3]=q0.w;
            pq[4]=q1.x; pq[5]=q1.y; pq[6]=q1.z;  pq[7]=q1.w;
            pq[8]=q2.x; pq[9]=q2.y; pq[10]=q2.z; pq[11]=q2.w;
            pq[12]=q3.x;pq[13]=q3.y;pq[14]=q3.z; pq[15]=q3.w;
        }

        // matvec partials for rows rr, rr+64
        float a00=0.f, a01=0.f, a10=0.f, a11=0.f;
        #pragma unroll
        for (int k = 0; k < 16; k += 2) {
            a00 = fmaf(E0[k],   pq[k],   a00);
            a01 = fmaf(E0[k+1], pq[k+1], a01);
            a10 = fmaf(E1[k],   pq[k],   a10);
            a11 = fmaf(E1[k+1], pq[k+1], a11);
        }
        float v0 = a00 + a01, v1 = a10 + a11;

        // every 4th step: measure max(p) off the critical path (p >= 0, DPP max tree)
        if ((t & 3) == 1) {
            float cm = pq[0];
            #pragma unroll
            for (int k = 1; k < 16; ++k) cm = fmaxf(cm, pq[k]);
            cm = fmaxf(cm, FDPP(cm, 0xB1));   // xor1 (quad_perm)
            cm = fmaxf(cm, FDPP(cm, 0x4E));   // xor2 (quad_perm)
            cm = fmaxf(cm, FDPP(cm, 0x141));  // row_half_mirror: 8-group
            cm = fmaxf(cm, FDPP(cm, 0x140));  // row_mirror: 16-group
            cm = fmaxf(cm, FDPP(cm, 0x142));  // row_bcast15: lane31/63 get 32-half max
            if ((tid & 31) == 31) wh[tid >> 5] = cm;
        }

        float ee_next = __expf(xld);   // off critical path

        // every 4th step (+1): fold 1/max into this step's write, log-accumulate
        if ((t & 3) == 2) {
            const float4* W = (const float4*)wh;
            float4 m0 = W[0], m1 = W[1], m2 = W[2], m3 = W[3];
            float mx = fmaxf(fmaxf(fmaxf(m0.x,m0.y), fmaxf(m0.z,m0.w)),
                             fmaxf(fmaxf(m1.x,m1.y), fmaxf(m1.z,m1.w)));
            mx = fmaxf(mx, fmaxf(fmaxf(fmaxf(m2.x,m2.y), fmaxf(m2.z,m2.w)),
                                 fmaxf(fmaxf(m3.x,m3.y), fmaxf(m3.z,m3.w))));
            inv = 1.0f / mx;
            logscale += __logf(mx);
        }

        // in-wave 8-way combine across chunks: 3 DPP add stages, no LDS, no barrier
        v0 += FDPP(v0, 0xB1); v0 += FDPP(v0, 0x4E); v0 += FDPP(v0, 0x141);
        v1 += FDPP(v1, 0xB1); v1 += FDPP(v1, 0x4E); v1 += FDPP(v1, 0x141);

        // publish p_{t+1} into the other buffer; ONE barrier per step
        if (writer) pbuf[cur ^ 1][pword(myrow)] = (w0 ? v0 : v1) * ee * inv;
        __syncthreads();
        if ((t & 3) == 2) inv = 1.f;
        ee = ee_next; xld = xnext; cur ^= 1;
    }

    // ---------------- logZ = logscale + log(sum p * exp(trans[END,:])) ----------------
    float z = 0.f;
    if (tid < 128) {
        z = pbuf[cur][pword(tid)] * __expf(trans[END_T * RN + tid]);
        #pragma unroll
        for (int off = 1; off < 64; off <<= 1) z += __shfl_xor(z, off, 64);
        if ((tid & 63) == 0) tmp8[tid >> 6] = z;
    }
    __syncthreads();
    if (tid == 0) out[b] = logscale + __logf(tmp8[0] + tmp8[1]) - goldv;
}

extern "C" void kernel_launch(void* const* d_in, const int* in_sizes, int n_in,
                              void* d_out, int out_size, void* d_ws, size_t ws_size,
                              hipStream_t stream) {
    const float* X     = (const float*)d_in[0];
    const int*   y     = (const int*)d_in[1];
    const float* trans = (const float*)d_in[2];
    float*       out   = (float*)d_out;

    const int B = out_size;            // 256
    const int L = in_sizes[1] / B;     // 1024

    crf_nll_kernel<<<dim3(B), dim3(512), 0, stream>>>(X, y, trans, out, L);
}

// Round 3
// 548.939 us; speedup vs baseline: 1.6631x; 1.1112x over previous
//
#include <hip/hip_runtime.h>

#define RN      128   // REAL
#define START_T 126
#define END_T   127

// DPP cross-lane helper (all-lane-active contexts only)
#define FDPP(x, ctrl) __int_as_float(__builtin_amdgcn_update_dpp(0, __float_as_int(x), (ctrl), 0xF, 0xF, true))

// padded p layout: row r -> word (r>>4)*20 + (r&15); 8 chunks of 16 at stride 20 (conflict-free b128)
__device__ __forceinline__ int pword(int r) { return ((r >> 4) * 20) + (r & 15); }

__global__ __launch_bounds__(512, 2)
void crf_nll_kernel(const float* __restrict__ X,
                    const int*   __restrict__ y,
                    const float* __restrict__ trans,
                    float* __restrict__ out, int L)
{
    const int b   = blockIdx.x;
    const int tid = threadIdx.x;
    const int s   = tid & 7;    // j-chunk 0..7 (16 wide)
    const int rr  = tid >> 3;   // 0..63 -> rows rr and rr+64
    const int wv  = tid >> 6;   // wave 0..7

    __shared__ __align__(16) float pb[2][160];    // double-buffered scaled probs (padded)
    __shared__ __align__(16) float earr[2][RN];   // double-buffered exp(emit)
    __shared__ float tmp8[8];

    const float* Xb = X + (size_t)b * (size_t)L * RN;
    const int*   yb = y + (size_t)b * L;

    // ---------------- gold path score ----------------
    float g = 0.f;
    for (int t = tid; t < L; t += 512) {
        int yt = yb[t];
        int yp = t ? yb[t - 1] : START_T;
        g += trans[yt * RN + yp] + Xb[(size_t)t * RN + yt];
    }
    #pragma unroll
    for (int off = 1; off < 64; off <<= 1) g += __shfl_xor(g, off, 64);
    if ((tid & 63) == 0) tmp8[wv] = g;

    // zero p buffers, seeding onehot(START) in buffer 0 in the same pass
    for (int w = tid; w < 320; w += 512)
        ((float*)pb)[w] = (w == pword(START_T)) ? 1.f : 0.f;

    // E = exp(trans) held in arch VGPRs (launch_bounds(512,2) -> 256-VGPR budget, no AGPR shuffling).
    // Masked entries (-1e4) underflow to exactly 0 -> semiring mask preserved.
    float E0[16], E1[16];
    {
        const float* t0 = trans + rr * RN + s * 16;
        const float* t1 = t0 + 64 * RN;
        #pragma unroll
        for (int k = 0; k < 16; ++k) { E0[k] = __expf(t0[k]); E1[k] = __expf(t1[k]); }
    }

    // emit team: waves 0,1 produce exp(X[t+1]) into earr during step t
    const bool team = (tid < RN);
    float xraw = 0.f;
    if (team) {
        earr[0][tid] = __expf(Xb[tid]);
        xraw = (L > 1) ? Xb[RN + tid] : Xb[tid];
    }

    const int erow = rr + ((s & 1) << 6);  // row whose emit this lane would apply (s<2 lanes write)
    const int wout = pword(erow);          // loop-invariant write slot

    float goldv = 0.f;
    __syncthreads();
    if (tid == 0) {
        float gg = 0.f;
        #pragma unroll
        for (int i = 0; i < 8; ++i) gg += tmp8[i];
        goldv = gg + trans[END_T * RN + yb[L - 1]];
    }

    float logscale = 0.f;

    auto step = [&](int t, const float* __restrict__ ps, float* __restrict__ pd,
                    const float* __restrict__ esrc, float* __restrict__ edst) {
        // emit pipeline (team waves only; wave-uniform branch)
        if (team) {
            edst[tid] = __expf(xraw);
            int tt = t + 2; if (tt > L - 1) tt = L - 1;
            xraw = Xb[(size_t)tt * RN + tid];
        }
        float ee = esrc[erow];   // exp(X[t][erow]); 2-way bank alias = free

        // my 16-wide chunk of p_t (conflict-free broadcast b128 reads)
        const float4* P4 = (const float4*)(ps + 20 * s);
        float4 q0 = P4[0], q1 = P4[1], q2 = P4[2], q3 = P4[3];
        float pq[16] = { q0.x,q0.y,q0.z,q0.w, q1.x,q1.y,q1.z,q1.w,
                         q2.x,q2.y,q2.z,q2.w, q3.x,q3.y,q3.z,q3.w };

        float a00 = 0.f, a01 = 0.f, a10 = 0.f, a11 = 0.f;
        #pragma unroll
        for (int k = 0; k < 16; k += 2) {
            a00 = fmaf(E0[k],   pq[k],   a00);
            a01 = fmaf(E0[k+1], pq[k+1], a01);
            a10 = fmaf(E1[k],   pq[k],   a10);
            a11 = fmaf(E1[k+1], pq[k+1], a11);
        }
        float v0 = a00 + a01, v1 = a10 + a11;

        // every 4th step: global max over p_t, computed redundantly per 8-lane group
        // (each group's chunks cover all 128 entries; identical result in every lane)
        float invv = 1.0f;
        if ((t & 3) == 2) {
            float m0 = fmaxf(fmaxf(pq[0], pq[1]),  fmaxf(pq[2], pq[3]));
            float m1 = fmaxf(fmaxf(pq[4], pq[5]),  fmaxf(pq[6], pq[7]));
            float m2 = fmaxf(fmaxf(pq[8], pq[9]),  fmaxf(pq[10], pq[11]));
            float m3 = fmaxf(fmaxf(pq[12], pq[13]), fmaxf(pq[14], pq[15]));
            float m = fmaxf(fmaxf(m0, m1), fmaxf(m2, m3));
            m = fmaxf(m, FDPP(m, 0xB1));    // xor1
            m = fmaxf(m, FDPP(m, 0x4E));    // xor2
            m = fmaxf(m, FDPP(m, 0x141));   // cross-quad within 8
            invv = 1.0f / m;
            logscale += __logf(m);
        }

        // 8-way cross-chunk combine: 3 DPP-add stages, no LDS
        v0 += FDPP(v0, 0xB1); v0 += FDPP(v0, 0x4E); v0 += FDPP(v0, 0x141);
        v1 += FDPP(v1, 0xB1); v1 += FDPP(v1, 0x4E); v1 += FDPP(v1, 0x141);

        if (s < 2) pd[wout] = (s ? v1 : v0) * (ee * invv);
        __syncthreads();   // ONE barrier per step
    };

    int t = 0;
    for (; t + 1 < L; t += 2) {
        step(t,     pb[0], pb[1], earr[0], earr[1]);
        step(t + 1, pb[1], pb[0], earr[1], earr[0]);
    }
    const float* pf = pb[0];
    if (t < L) { step(t, pb[0], pb[1], earr[0], earr[1]); pf = pb[1]; }

    // ---------------- logZ = logscale + log(sum p_L * exp(trans[END,:])) ----------------
    float z = 0.f;
    if (tid < RN) {
        z = pf[pword(tid)] * __expf(trans[END_T * RN + tid]);
        #pragma unroll
        for (int off = 1; off < 64; off <<= 1) z += __shfl_xor(z, off, 64);
        if ((tid & 63) == 0) tmp8[tid >> 6] = z;
    }
    __syncthreads();
    if (tid == 0) out[b] = logscale + __logf(tmp8[0] + tmp8[1]) - goldv;
}

extern "C" void kernel_launch(void* const* d_in, const int* in_sizes, int n_in,
                              void* d_out, int out_size, void* d_ws, size_t ws_size,
                              hipStream_t stream) {
    const float* X     = (const float*)d_in[0];
    const int*   y     = (const int*)d_in[1];
    const float* trans = (const float*)d_in[2];
    float*       out   = (float*)d_out;

    const int B = out_size;            // 256
    const int L = in_sizes[1] / B;     // 1024

    crf_nll_kernel<<<dim3(B), dim3(512), 0, stream>>>(X, y, trans, out, L);
}